// Round 1
// baseline (346.771 us; speedup 1.0000x reference)
//
#include <hip/hip_runtime.h>

// CascadedAttentionCell: B=64, T=512, D=1024, OUT=1024 (all fp32 in/out)
//   WaS = prev@Wa + Ba;  UaH = inputs@Ua (68.7 GFLOP, fp16 MFMA);
//   scores = relu(tanh(UaH+WaS+Ba)@Va); sm = softmax_T; out = sum_t inputs*sm
// Design R0: Ua pre-packed to fp16 in B-fragment order (coalesced dwordx4 frag
// loads, no LDS for B); A staged fp32->fp16 via LDS (stride 136 = 16B-aligned);
// wave tile 64x128 via 2x4 of mfma_f32_32x32x16_f16; fused tanh+Va epilogue.

#define NBATCH 64
#define NT     512
#define NDIM   1024
#define NOUT   1024

typedef _Float16 h8 __attribute__((ext_vector_type(8)));
typedef _Float16 h4 __attribute__((ext_vector_type(4)));
typedef float f16v __attribute__((ext_vector_type(16)));

__device__ __forceinline__ float tanh_fast(float x) {
    // tanh(x) = 1 - 2/(exp(2x)+1); exp inf/0 limits give +-1 correctly
    float e = __expf(2.0f * x);
    return 1.0f - 2.0f * __builtin_amdgcn_rcpf(e + 1.0f);
}

// ---- K2a: pack Ua (fp32 [K=1024][N=1024]) into fp16 B-fragment order ----
// Block (nt,ks) covers n in [nt*32,+32), k in [ks*16,+16); 512 fp16 per block,
// lane-major: lane = ((k&15)>>3)*32 + (n&31) holds k&7 contiguous.
__global__ __launch_bounds__(256) void k_pack_ua(const float* __restrict__ Ua,
                                                 _Float16* __restrict__ B16) {
    int t = blockIdx.x * 256 + threadIdx.x;   // 0..1048575
    int k = t >> 10, n = t & 1023;
    int nt = n >> 5, nn = n & 31;
    int ks = k >> 4, kg = (k >> 3) & 1, j = k & 7;
    int pos = (((nt << 6) + ks) << 9) + (((kg << 5) + nn) << 3) + j;
    B16[pos] = (_Float16)Ua[t];
}

// ---- K1: WaS partials: part[oc][b][p] = sum_{o in chunk} ps[b][o]*Wa[o][p] ----
__global__ __launch_bounds__(256) void k_was_part(const float* __restrict__ ps,
                                                  const float* __restrict__ Wa,
                                                  float* __restrict__ part) {
    int oc = blockIdx.x, b = blockIdx.y, tid = threadIdx.x;
    const float4* Wa4 = (const float4*)Wa;
    const float* psb = ps + b * 1024;
    float4 acc = {0.f, 0.f, 0.f, 0.f};
    int o0 = oc * 128;
#pragma unroll 4
    for (int o = o0; o < o0 + 128; ++o) {
        float s = psb[o];
        float4 wv = Wa4[o * 256 + tid];
        acc.x += s * wv.x; acc.y += s * wv.y; acc.z += s * wv.z; acc.w += s * wv.w;
    }
    ((float4*)part)[((oc << 6) + b) * 256 + tid] = acc;
}

// ---- K1b: wsWaS[b][p] = Ba[p] + sum_oc part ----
__global__ __launch_bounds__(256) void k_was_reduce(const float* __restrict__ part,
                                                    const float* __restrict__ Ba,
                                                    float* __restrict__ wsWaS) {
    int b = blockIdx.x, tid = threadIdx.x;
    const float4* p4 = (const float4*)part;
    float4 acc = ((const float4*)Ba)[tid];
#pragma unroll
    for (int oc = 0; oc < 8; ++oc) {
        float4 v = p4[((oc << 6) + b) * 256 + tid];
        acc.x += v.x; acc.y += v.y; acc.z += v.z; acc.w += v.w;
    }
    ((float4*)wsWaS)[b * 256 + tid] = acc;
}

// ---- K3: fused  scores[r] = relu( sum_n tanh(UaH[r][n]+wsWaS[b][n]) * Va[n] ) ----
#define ASH_STRIDE 136   // fp16 units; 272 B rows: 16B-aligned for ds_read_b128
__global__ __launch_bounds__(256, 2) void k_fused_gemm(
    const float* __restrict__ inputs, const _Float16* __restrict__ B16,
    const float* __restrict__ wsWaS, const float* __restrict__ Va,
    float* __restrict__ scores)
{
    __shared__ _Float16 Ash[64 * ASH_STRIDE];
    __shared__ float scoreSh[64];
    const int tid = threadIdx.x;
    const int lane = tid & 63, wv = tid >> 6;
    const int l31 = lane & 31, lhi = lane >> 5;
    const int r0 = blockIdx.x * 64;
    const int b = r0 >> 9;              // 512 rows per batch, 64 | 512
    const int srow = tid >> 2, sq = tid & 3;
    const float4* inF4 = (const float4*)inputs;

    if (tid < 64) scoreSh[tid] = 0.0f;   // first barrier below publishes this

    for (int pass = 0; pass < 2; ++pass) {
        const int c0w = pass * 512 + wv * 128;   // this wave's col base
        const int ntb = c0w >> 5;                // base n-tile index
        f16v acc[2][4];
#pragma unroll
        for (int rt = 0; rt < 2; ++rt)
#pragma unroll
            for (int ct = 0; ct < 4; ++ct)
#pragma unroll
                for (int e = 0; e < 16; ++e) acc[rt][ct][e] = 0.0f;

        for (int kc = 0; kc < 8; ++kc) {        // K chunks of 128
            const int k0 = kc * 128;
            __syncthreads();                     // prior reads of Ash done
            {   // stage A tile: 64 rows x 128 k, fp32 -> fp16
                const float4* src = inF4 + (size_t)(r0 + srow) * 256 + (k0 >> 2) + sq * 8;
                _Float16* dst = &Ash[srow * ASH_STRIDE + sq * 32];
#pragma unroll
                for (int jj = 0; jj < 8; ++jj) {
                    float4 v = src[jj];
                    h4 hv = { (_Float16)v.x, (_Float16)v.y, (_Float16)v.z, (_Float16)v.w };
                    *(h4*)(dst + jj * 4) = hv;
                }
            }
            __syncthreads();
#pragma unroll
            for (int ks8 = 0; ks8 < 8; ++ks8) {  // k-steps of 16
                const int ks = kc * 8 + ks8;
                h8 a0 = *(const h8*)&Ash[l31 * ASH_STRIDE + ks8 * 16 + lhi * 8];
                h8 a1 = *(const h8*)&Ash[(32 + l31) * ASH_STRIDE + ks8 * 16 + lhi * 8];
#pragma unroll
                for (int ct = 0; ct < 4; ++ct) {
                    const h8 bf = *(const h8*)(B16 +
                        ((size_t)(((ntb + ct) << 6) + ks) << 9) + lane * 8);
                    acc[0][ct] = __builtin_amdgcn_mfma_f32_32x32x16_f16(a0, bf, acc[0][ct], 0, 0, 0);
                    acc[1][ct] = __builtin_amdgcn_mfma_f32_32x32x16_f16(a1, bf, acc[1][ct], 0, 0, 0);
                }
            }
        }
        // epilogue: tanh + Va dot, reduce over this pass's 128 cols
        float wsv[4], vav[4];
#pragma unroll
        for (int ct = 0; ct < 4; ++ct) {
            int n = c0w + ct * 32 + l31;
            wsv[ct] = wsWaS[b * 1024 + n];
            vav[ct] = Va[n];
        }
#pragma unroll
        for (int rt = 0; rt < 2; ++rt) {
#pragma unroll
            for (int i = 0; i < 16; ++i) {
                float s = 0.0f;
#pragma unroll
                for (int ct = 0; ct < 4; ++ct)
                    s += tanh_fast(acc[rt][ct][i] + wsv[ct]) * vav[ct];
                s += __shfl_xor(s, 1);
                s += __shfl_xor(s, 2);
                s += __shfl_xor(s, 4);
                s += __shfl_xor(s, 8);
                s += __shfl_xor(s, 16);
                if (l31 == 0) {
                    // C/D layout (verified m74/m101): row=(reg&3)+8*(reg>>2)+4*(lane>>5)
                    int row = rt * 32 + (i & 3) + ((i >> 2) << 3) + (lhi << 2);
                    atomicAdd(&scoreSh[row], s);
                }
            }
        }
    }
    __syncthreads();
    if (tid < 64) scores[r0 + tid] = fmaxf(scoreSh[tid], 0.0f);   // relu here
}

// ---- K4: softmax over T=512 per batch ----
__global__ __launch_bounds__(256) void k_softmax(const float* __restrict__ scores,
                                                 float* __restrict__ sm) {
    int b = blockIdx.x, tid = threadIdx.x;
    __shared__ float red[256];
    const float* sb = scores + b * 512;
    float s0 = sb[tid], s1 = sb[tid + 256];
    red[tid] = fmaxf(s0, s1);
    __syncthreads();
    for (int st = 128; st > 0; st >>= 1) {
        if (tid < st) red[tid] = fmaxf(red[tid], red[tid + st]);
        __syncthreads();
    }
    float m = red[0];
    __syncthreads();
    float e0 = __expf(s0 - m), e1 = __expf(s1 - m);
    red[tid] = e0 + e1;
    __syncthreads();
    for (int st = 128; st > 0; st >>= 1) {
        if (tid < st) red[tid] += red[tid + st];
        __syncthreads();
    }
    float inv = 1.0f / red[0];
    sm[b * 512 + tid] = e0 * inv;
    sm[b * 512 + 256 + tid] = e1 * inv;
}

// ---- K5: context partials over 64-timestep slices ----
__global__ __launch_bounds__(256) void k_ctx_part(const float* __restrict__ inputs,
                                                  const float* __restrict__ sm,
                                                  float* __restrict__ part) {
    int ts = blockIdx.x, b = blockIdx.y, tid = threadIdx.x;
    const float4* inF4 = (const float4*)inputs;
    float4 acc = {0.f, 0.f, 0.f, 0.f};
    int t0 = ts * 64;
#pragma unroll 4
    for (int t = t0; t < t0 + 64; ++t) {
        float wgt = sm[b * 512 + t];
        float4 x = inF4[(size_t)(b * 512 + t) * 256 + tid];
        acc.x += wgt * x.x; acc.y += wgt * x.y; acc.z += wgt * x.z; acc.w += wgt * x.w;
    }
    ((float4*)part)[((ts << 6) + b) * 256 + tid] = acc;
}

// ---- K6: reduce 8 slices -> d_out ----
__global__ __launch_bounds__(256) void k_ctx_reduce(const float* __restrict__ part,
                                                    float* __restrict__ out) {
    int g = blockIdx.x * 256 + threadIdx.x;   // 0..16383 float4 slots
    const float4* p4 = (const float4*)part;
    float4 acc = p4[g];
#pragma unroll
    for (int s = 1; s < 8; ++s) {
        float4 v = p4[s * 16384 + g];
        acc.x += v.x; acc.y += v.y; acc.z += v.z; acc.w += v.w;
    }
    ((float4*)out)[g] = acc;
}

extern "C" void kernel_launch(void* const* d_in, const int* in_sizes, int n_in,
                              void* d_out, int out_size, void* d_ws, size_t ws_size,
                              hipStream_t stream) {
    const float* inputs = (const float*)d_in[0];   // [64,512,1024]
    const float* prev   = (const float*)d_in[1];   // [64,1024]
    const float* Wa     = (const float*)d_in[2];   // [1024,1024]
    const float* Ua     = (const float*)d_in[3];   // [1024,1024]
    const float* Va     = (const float*)d_in[4];   // [1024]
    const float* Ba     = (const float*)d_in[5];   // [1024]
    float* out = (float*)d_out;

    char* ws = (char*)d_ws;                          // ~6.6 MB used
    _Float16* B16   = (_Float16*)(ws);               // 2 MB packed Ua
    float* wasPart  = (float*)(ws + (2u << 20));     // 2 MB
    float* wsWaS    = (float*)(ws + (4u << 20));     // 256 KB
    float* scores   = (float*)(ws + (4u << 20) + (256u << 10));  // 128 KB
    float* sm       = (float*)(ws + (4u << 20) + (384u << 10));  // 128 KB
    float* ctxPart  = (float*)(ws + (4u << 20) + (512u << 10));  // 2 MB

    hipLaunchKernelGGL(k_pack_ua,    dim3(4096),   dim3(256), 0, stream, Ua, B16);
    hipLaunchKernelGGL(k_was_part,   dim3(8, 64),  dim3(256), 0, stream, prev, Wa, wasPart);
    hipLaunchKernelGGL(k_was_reduce, dim3(64),     dim3(256), 0, stream, wasPart, Ba, wsWaS);
    hipLaunchKernelGGL(k_fused_gemm, dim3(512),    dim3(256), 0, stream, inputs, B16, wsWaS, Va, scores);
    hipLaunchKernelGGL(k_softmax,    dim3(64),     dim3(256), 0, stream, scores, sm);
    hipLaunchKernelGGL(k_ctx_part,   dim3(8, 64),  dim3(256), 0, stream, inputs, sm, ctxPart);
    hipLaunchKernelGGL(k_ctx_reduce, dim3(64),     dim3(256), 0, stream, ctxPart, out);
}

// Round 2
// 342.648 us; speedup vs baseline: 1.0120x; 1.0120x over previous
//
#include <hip/hip_runtime.h>

// CascadedAttentionCell: B=64, T=512, D=1024, OUT=1024 (all fp32 in/out)
//   WaS = prev@Wa + Ba;  UaH = inputs@Ua (68.7 GFLOP, fp16 MFMA);
//   scores = relu(tanh(UaH+WaS+Ba)@Va); sm = softmax_T; out = sum_t inputs*sm
// R2: software-pipelined GEMM — register prefetch of next A chunk + LDS double
// buffer (one barrier per chunk, no vmcnt(0) drain of HBM loads before it);
// B-frags batched per k-step. k_pack_ua rewritten to 16B stores.

#define NBATCH 64
#define NT     512
#define NDIM   1024
#define NOUT   1024

typedef _Float16 h8 __attribute__((ext_vector_type(8)));
typedef _Float16 h4 __attribute__((ext_vector_type(4)));
typedef float f16v __attribute__((ext_vector_type(16)));

__device__ __forceinline__ float tanh_fast(float x) {
    float e = __expf(2.0f * x);
    return 1.0f - 2.0f * __builtin_amdgcn_rcpf(e + 1.0f);
}

// ---- K2a: pack Ua (fp32 [K=1024][N=1024]) into fp16 B-fragment order ----
// t = ((nt*64+ks)*64) + kg*32 + nn ; thread writes 8 contiguous fp16 (16 B).
__global__ __launch_bounds__(256) void k_pack_ua(const float* __restrict__ Ua,
                                                 _Float16* __restrict__ B16) {
    int t = blockIdx.x * 256 + threadIdx.x;   // 0..131071
    int nn = t & 31, kg = (t >> 5) & 1, ks = (t >> 6) & 63, nt = t >> 12;
    int n = (nt << 5) + nn;
    int kbase = (ks << 4) + (kg << 3);
    h8 v;
#pragma unroll
    for (int j = 0; j < 8; ++j) v[j] = (_Float16)Ua[(size_t)(kbase + j) * 1024 + n];
    *(h8*)(B16 + ((size_t)t << 3)) = v;
}

// ---- K1: WaS partials: part[oc][b][p] = sum_{o in chunk} ps[b][o]*Wa[o][p] ----
__global__ __launch_bounds__(256) void k_was_part(const float* __restrict__ ps,
                                                  const float* __restrict__ Wa,
                                                  float* __restrict__ part) {
    int oc = blockIdx.x, b = blockIdx.y, tid = threadIdx.x;
    const float4* Wa4 = (const float4*)Wa;
    const float* psb = ps + b * 1024;
    float4 acc = {0.f, 0.f, 0.f, 0.f};
    int o0 = oc * 128;
#pragma unroll 4
    for (int o = o0; o < o0 + 128; ++o) {
        float s = psb[o];
        float4 wv = Wa4[o * 256 + tid];
        acc.x += s * wv.x; acc.y += s * wv.y; acc.z += s * wv.z; acc.w += s * wv.w;
    }
    ((float4*)part)[((oc << 6) + b) * 256 + tid] = acc;
}

// ---- K1b: wsWaS[b][p] = Ba[p] + sum_oc part ----
__global__ __launch_bounds__(256) void k_was_reduce(const float* __restrict__ part,
                                                    const float* __restrict__ Ba,
                                                    float* __restrict__ wsWaS) {
    int b = blockIdx.x, tid = threadIdx.x;
    const float4* p4 = (const float4*)part;
    float4 acc = ((const float4*)Ba)[tid];
#pragma unroll
    for (int oc = 0; oc < 8; ++oc) {
        float4 v = p4[((oc << 6) + b) * 256 + tid];
        acc.x += v.x; acc.y += v.y; acc.z += v.z; acc.w += v.w;
    }
    ((float4*)wsWaS)[b * 256 + tid] = acc;
}

// ---- K3: fused  scores[r] = relu( sum_n tanh(UaH[r][n]+wsWaS[b][n]) * Va[n] ) ----
#define ASH_STRIDE 136   // fp16 units; 272 B rows: 16B-aligned, negligible conflicts
__global__ __launch_bounds__(256, 2) void k_fused_gemm(
    const float* __restrict__ inputs, const _Float16* __restrict__ B16,
    const float* __restrict__ wsWaS, const float* __restrict__ Va,
    float* __restrict__ scores)
{
    __shared__ _Float16 Ash[2][64 * ASH_STRIDE];
    __shared__ float scoreSh[64];
    const int tid = threadIdx.x;
    const int lane = tid & 63, wv = tid >> 6;
    const int l31 = lane & 31, lhi = lane >> 5;
    const int r0 = blockIdx.x * 64;
    const int b = r0 >> 9;
    const int srow = tid >> 2, sq = tid & 3;
    const float4* srcBase = (const float4*)inputs + (size_t)(r0 + srow) * 256 + sq * 8;

    if (tid < 64) scoreSh[tid] = 0.0f;

    float4 vA[8];
#pragma unroll
    for (int j = 0; j < 8; ++j) vA[j] = srcBase[j];          // chunk 0
    {
        _Float16* dst = &Ash[0][srow * ASH_STRIDE + sq * 32];
#pragma unroll
        for (int j = 0; j < 8; ++j) {
            float4 v = vA[j];
            *(h4*)(dst + j * 4) =
                (h4){ (_Float16)v.x, (_Float16)v.y, (_Float16)v.z, (_Float16)v.w };
        }
    }
    __syncthreads();

    for (int pass = 0; pass < 2; ++pass) {
        const int c0w = pass * 512 + wv * 128;
        const int ntb = c0w >> 5;
        f16v acc[2][4];
#pragma unroll
        for (int rt = 0; rt < 2; ++rt)
#pragma unroll
            for (int ct = 0; ct < 4; ++ct)
#pragma unroll
                for (int e = 0; e < 16; ++e) acc[rt][ct][e] = 0.0f;

        for (int kc = 0; kc < 8; ++kc) {
            const int buf = kc & 1;
            const bool pf = !(pass == 1 && kc == 7);
            if (pf) {   // issue next chunk's HBM loads before the MFMAs
                const float4* src = srcBase + (((kc + 1) & 7) << 5);
#pragma unroll
                for (int j = 0; j < 8; ++j) vA[j] = src[j];
            }
#pragma unroll
            for (int ks8 = 0; ks8 < 8; ++ks8) {
                const int ks = kc * 8 + ks8;
                h8 a0 = *(const h8*)&Ash[buf][l31 * ASH_STRIDE + ks8 * 16 + lhi * 8];
                h8 a1 = *(const h8*)&Ash[buf][(32 + l31) * ASH_STRIDE + ks8 * 16 + lhi * 8];
                h8 bf[4];
#pragma unroll
                for (int ct = 0; ct < 4; ++ct)
                    bf[ct] = *(const h8*)(B16 +
                        ((size_t)(((ntb + ct) << 6) + ks) << 9) + lane * 8);
#pragma unroll
                for (int ct = 0; ct < 4; ++ct) {
                    acc[0][ct] = __builtin_amdgcn_mfma_f32_32x32x16_f16(a0, bf[ct], acc[0][ct], 0, 0, 0);
                    acc[1][ct] = __builtin_amdgcn_mfma_f32_32x32x16_f16(a1, bf[ct], acc[1][ct], 0, 0, 0);
                }
            }
            if (pf) {   // loads have drained during MFMAs; convert + stage
                _Float16* dst = &Ash[buf ^ 1][srow * ASH_STRIDE + sq * 32];
#pragma unroll
                for (int j = 0; j < 8; ++j) {
                    float4 v = vA[j];
                    *(h4*)(dst + j * 4) =
                        (h4){ (_Float16)v.x, (_Float16)v.y, (_Float16)v.z, (_Float16)v.w };
                }
            }
            __syncthreads();
        }
        // epilogue: tanh + Va dot, reduce over this pass's 128 cols
        float wsv[4], vav[4];
#pragma unroll
        for (int ct = 0; ct < 4; ++ct) {
            int n = c0w + ct * 32 + l31;
            wsv[ct] = wsWaS[b * 1024 + n];
            vav[ct] = Va[n];
        }
#pragma unroll
        for (int rt = 0; rt < 2; ++rt) {
#pragma unroll
            for (int i = 0; i < 16; ++i) {
                float s = 0.0f;
#pragma unroll
                for (int ct = 0; ct < 4; ++ct)
                    s += tanh_fast(acc[rt][ct][i] + wsv[ct]) * vav[ct];
                s += __shfl_xor(s, 1);
                s += __shfl_xor(s, 2);
                s += __shfl_xor(s, 4);
                s += __shfl_xor(s, 8);
                s += __shfl_xor(s, 16);
                if (l31 == 0) {
                    int row = rt * 32 + (i & 3) + ((i >> 2) << 3) + (lhi << 2);
                    atomicAdd(&scoreSh[row], s);
                }
            }
        }
    }
    __syncthreads();
    if (tid < 64) scores[r0 + tid] = fmaxf(scoreSh[tid], 0.0f);
}

// ---- K4: softmax over T=512 per batch ----
__global__ __launch_bounds__(256) void k_softmax(const float* __restrict__ scores,
                                                 float* __restrict__ sm) {
    int b = blockIdx.x, tid = threadIdx.x;
    __shared__ float red[256];
    const float* sb = scores + b * 512;
    float s0 = sb[tid], s1 = sb[tid + 256];
    red[tid] = fmaxf(s0, s1);
    __syncthreads();
    for (int st = 128; st > 0; st >>= 1) {
        if (tid < st) red[tid] = fmaxf(red[tid], red[tid + st]);
        __syncthreads();
    }
    float m = red[0];
    __syncthreads();
    float e0 = __expf(s0 - m), e1 = __expf(s1 - m);
    red[tid] = e0 + e1;
    __syncthreads();
    for (int st = 128; st > 0; st >>= 1) {
        if (tid < st) red[tid] += red[tid + st];
        __syncthreads();
    }
    float inv = 1.0f / red[0];
    sm[b * 512 + tid] = e0 * inv;
    sm[b * 512 + 256 + tid] = e1 * inv;
}

// ---- K5: context partials over 64-timestep slices ----
__global__ __launch_bounds__(256) void k_ctx_part(const float* __restrict__ inputs,
                                                  const float* __restrict__ sm,
                                                  float* __restrict__ part) {
    int ts = blockIdx.x, b = blockIdx.y, tid = threadIdx.x;
    const float4* inF4 = (const float4*)inputs;
    float4 acc = {0.f, 0.f, 0.f, 0.f};
    int t0 = ts * 64;
#pragma unroll 8
    for (int t = t0; t < t0 + 64; ++t) {
        float wgt = sm[b * 512 + t];
        float4 x = inF4[(size_t)(b * 512 + t) * 256 + tid];
        acc.x += wgt * x.x; acc.y += wgt * x.y; acc.z += wgt * x.z; acc.w += wgt * x.w;
    }
    ((float4*)part)[((ts << 6) + b) * 256 + tid] = acc;
}

// ---- K6: reduce 8 slices -> d_out ----
__global__ __launch_bounds__(256) void k_ctx_reduce(const float* __restrict__ part,
                                                    float* __restrict__ out) {
    int g = blockIdx.x * 256 + threadIdx.x;
    const float4* p4 = (const float4*)part;
    float4 acc = p4[g];
#pragma unroll
    for (int s = 1; s < 8; ++s) {
        float4 v = p4[s * 16384 + g];
        acc.x += v.x; acc.y += v.y; acc.z += v.z; acc.w += v.w;
    }
    ((float4*)out)[g] = acc;
}

extern "C" void kernel_launch(void* const* d_in, const int* in_sizes, int n_in,
                              void* d_out, int out_size, void* d_ws, size_t ws_size,
                              hipStream_t stream) {
    const float* inputs = (const float*)d_in[0];
    const float* prev   = (const float*)d_in[1];
    const float* Wa     = (const float*)d_in[2];
    const float* Ua     = (const float*)d_in[3];
    const float* Va     = (const float*)d_in[4];
    const float* Ba     = (const float*)d_in[5];
    float* out = (float*)d_out;

    char* ws = (char*)d_ws;
    _Float16* B16   = (_Float16*)(ws);               // 2 MB packed Ua
    float* wasPart  = (float*)(ws + (2u << 20));     // 2 MB
    float* wsWaS    = (float*)(ws + (4u << 20));     // 256 KB
    float* scores   = (float*)(ws + (4u << 20) + (256u << 10));  // 128 KB
    float* sm       = (float*)(ws + (4u << 20) + (384u << 10));  // 128 KB
    float* ctxPart  = (float*)(ws + (4u << 20) + (512u << 10));  // 2 MB

    hipLaunchKernelGGL(k_pack_ua,    dim3(512),    dim3(256), 0, stream, Ua, B16);
    hipLaunchKernelGGL(k_was_part,   dim3(8, 64),  dim3(256), 0, stream, prev, Wa, wasPart);
    hipLaunchKernelGGL(k_was_reduce, dim3(64),     dim3(256), 0, stream, wasPart, Ba, wsWaS);
    hipLaunchKernelGGL(k_fused_gemm, dim3(512),    dim3(256), 0, stream, inputs, B16, wsWaS, Va, scores);
    hipLaunchKernelGGL(k_softmax,    dim3(64),     dim3(256), 0, stream, scores, sm);
    hipLaunchKernelGGL(k_ctx_part,   dim3(8, 64),  dim3(256), 0, stream, inputs, sm, ctxPart);
    hipLaunchKernelGGL(k_ctx_reduce, dim3(64),     dim3(256), 0, stream, ctxPart, out);
}